// Round 9
// baseline (1030.318 us; speedup 1.0000x reference)
//
#include <hip/hip_runtime.h>
#include <hip/hip_bf16.h>
#include <math.h>

#define Tn 1024
#define Cn 960
#define Hn 15
#define Nn 64
#define Mn 4096  // B*T

typedef short bf16x8 __attribute__((ext_vector_type(8)));
typedef float f32x4 __attribute__((ext_vector_type(4)));

#define MCc ((size_t)Mn * Cn)

__device__ __forceinline__ float sigmf(float x) { return 1.0f / (1.0f + __expf(-x)); }

// round-to-nearest-even f32 -> bf16 (as ushort)
__device__ __forceinline__ ushort f2bf(float x) {
    unsigned u = __float_as_uint(x);
    unsigned r = (u + 0x7FFFu + ((u >> 16) & 1u)) >> 16;
    return (ushort)r;
}
__device__ __forceinline__ float bf2f(ushort h) { return __uint_as_float(((unsigned)h) << 16); }

// full sum over the 16-lane DPP row via row_ror rotate-accumulate (all VALU).
__device__ __forceinline__ float rowsum16(float x) {
    x += __int_as_float(__builtin_amdgcn_update_dpp(0, __float_as_int(x), 0x121, 0xF, 0xF, true)); // ror:1
    x += __int_as_float(__builtin_amdgcn_update_dpp(0, __float_as_int(x), 0x122, 0xF, 0xF, true)); // ror:2
    x += __int_as_float(__builtin_amdgcn_update_dpp(0, __float_as_int(x), 0x124, 0xF, 0xF, true)); // ror:4
    x += __int_as_float(__builtin_amdgcn_update_dpp(0, __float_as_int(x), 0x128, 0xF, 0xF, true)); // ror:8
    return x;
}

// ---------------------------------------------------------------------------
// token-shift + 6 mixes; r/k/v emitted as split-bf16 pairs (hi @p, lo @p+MC),
// w/a/g/v emitted f32.
// ---------------------------------------------------------------------------
__global__ __launch_bounds__(256) void mix6_kernel(
    const float* __restrict__ x,
    const float* __restrict__ mr, const float* __restrict__ mw, const float* __restrict__ mk,
    const float* __restrict__ mv, const float* __restrict__ ma, const float* __restrict__ mg,
    ushort* __restrict__ r_sp, float* __restrict__ o_w, ushort* __restrict__ k_sp,
    float* __restrict__ o_v, ushort* __restrict__ v_sp,
    float* __restrict__ o_a, float* __restrict__ o_g)
{
    int idx = blockIdx.x * 256 + threadIdx.x;  // float4 index
    int e = idx * 4;
    if (e >= Mn * Cn) return;
    int m = e / Cn;
    int c = e - m * Cn;
    int t = m & (Tn - 1);
    float4 xv = *(const float4*)(x + e);
    float4 xp = make_float4(0.f, 0.f, 0.f, 0.f);
    if (t > 0) xp = *(const float4*)(x + e - Cn);
    float4 dx = make_float4(xp.x - xv.x, xp.y - xv.y, xp.z - xv.z, xp.w - xv.w);
#define MIXV(MIXP, O)                                                         \
    float4 O;                                                                 \
    {                                                                         \
        float4 mm = *(const float4*)(MIXP + c);                               \
        O = make_float4(xv.x + dx.x * mm.x, xv.y + dx.y * mm.y,               \
                        xv.z + dx.z * mm.z, xv.w + dx.w * mm.w);              \
    }
#define SPLITW(O, P)                                                          \
    {                                                                         \
        ushort h0 = f2bf(O.x), h1 = f2bf(O.y), h2 = f2bf(O.z), h3 = f2bf(O.w);\
        ushort l0 = f2bf(O.x - bf2f(h0)), l1 = f2bf(O.y - bf2f(h1));          \
        ushort l2 = f2bf(O.z - bf2f(h2)), l3 = f2bf(O.w - bf2f(h3));          \
        *(ushort4*)(P + e) = make_ushort4(h0, h1, h2, h3);                    \
        *(ushort4*)(P + MCc + e) = make_ushort4(l0, l1, l2, l3);              \
    }
    MIXV(mr, orv) SPLITW(orv, r_sp)
    MIXV(mw, owv) *(float4*)(o_w + e) = owv;
    MIXV(mk, okv) SPLITW(okv, k_sp)
    MIXV(mv, ovv) *(float4*)(o_v + e) = ovv; SPLITW(ovv, v_sp)
    MIXV(ma, oav) *(float4*)(o_a + e) = oav;
    MIXV(mg, ogv) *(float4*)(o_g + e) = ogv;
#undef SPLITW
#undef MIXV
}

// ---------------------------------------------------------------------------
// split-convert activation: f32 [Mn][Cn] -> hi/lo bf16 (ushort) arrays
// ---------------------------------------------------------------------------
__global__ __launch_bounds__(256) void convA_kernel(
    const float* __restrict__ X, ushort* __restrict__ hi, ushort* __restrict__ lo)
{
    int idx = blockIdx.x * 256 + threadIdx.x;
    int e = idx * 4;
    if (e >= Mn * Cn) return;
    float4 x = *(const float4*)(X + e);
    ushort h0 = f2bf(x.x), h1 = f2bf(x.y), h2 = f2bf(x.z), h3 = f2bf(x.w);
    ushort l0 = f2bf(x.x - bf2f(h0)), l1 = f2bf(x.y - bf2f(h1));
    ushort l2 = f2bf(x.z - bf2f(h2)), l3 = f2bf(x.w - bf2f(h3));
    *(ushort4*)(hi + e) = make_ushort4(h0, h1, h2, h3);
    *(ushort4*)(lo + e) = make_ushort4(l0, l1, l2, l3);
}

// ---------------------------------------------------------------------------
// transpose + split-convert weight: W f32 [K=960][N=960] -> Thi/Tlo bf16 [N][K]
// ---------------------------------------------------------------------------
__global__ __launch_bounds__(256) void convWT_kernel(
    const float* __restrict__ W, ushort* __restrict__ Thi, ushort* __restrict__ Tlo)
{
    __shared__ float tile[32][33];
    int k0 = blockIdx.x * 32, n0 = blockIdx.y * 32;
    int tx = threadIdx.x & 31, ty = threadIdx.x >> 5;  // 32 x 8
#pragma unroll
    for (int i = 0; i < 4; ++i)
        tile[ty + 8 * i][tx] = W[(size_t)(k0 + ty + 8 * i) * 960 + n0 + tx];
    __syncthreads();
#pragma unroll
    for (int i = 0; i < 4; ++i) {
        float x = tile[tx][ty + 8 * i];
        ushort h = f2bf(x);
        ushort l = f2bf(x - bf2f(h));
        size_t o = (size_t)(n0 + ty + 8 * i) * 960 + k0 + tx;
        Thi[o] = h;
        Tlo[o] = l;
    }
}

// ---------------------------------------------------------------------------
// split-bf16 MFMA GEMM, 512 threads / 8 waves: C = A @ W, K=960, via
// Ahi@Whi + Ahi@Wlo + Alo@Whi.  BM=128 BN=64 BK=32; wave w owns rows
// [16w,16w+16): 12 mfma + 10 ds_read_b128 per k-step. LDS 61KB ->
// 2 blocks/CU -> 4 waves/SIMD (stall cover).
// ---------------------------------------------------------------------------
__global__ __launch_bounds__(512) void gemm_bf3_kernel(
    const ushort* __restrict__ Ahi, const ushort* __restrict__ Alo,
    const ushort* __restrict__ Bhi, const ushort* __restrict__ Blo,
    float* __restrict__ C, int ldc)
{
    __shared__ __align__(16) ushort sA[2][2][128][40];  // 40960 B
    __shared__ __align__(16) ushort sB[2][2][64][40];   // 20480 B
    const int K = 960;
    int bm = blockIdx.x * 128, bn = blockIdx.y * 64;
    int t = threadIdx.x;
    int w = t >> 6, l = t & 63;
    int lr = l & 15, lk = l >> 4;

    int ar = t >> 2, aseg = t & 3;                  // A: 128 rows, 4 thr/row, 8 ushorts
    int brr = t >> 2;                               // B: 64 rows x 2 halves
    int bhl = brr >> 6, brow = brr & 63, bseg = t & 3;
    const ushort* gAh = Ahi + (size_t)(bm + ar) * K + aseg * 8;
    const ushort* gAl = Alo + (size_t)(bm + ar) * K + aseg * 8;
    const ushort* gB = (bhl ? Blo : Bhi) + (size_t)(bn + brow) * K + bseg * 8;

    f32x4 acc[4];
#pragma unroll
    for (int j = 0; j < 4; ++j)
#pragma unroll
        for (int e = 0; e < 4; ++e) acc[j][e] = 0.f;

    float4 rh, rl, rb;
#define LOADK(KOFF)                                                           \
    {                                                                         \
        rh = *(const float4*)(gAh + (KOFF));                                  \
        rl = *(const float4*)(gAl + (KOFF));                                  \
        rb = *(const float4*)(gB + (KOFF));                                   \
    }
#define WRITEK(BUF)                                                           \
    {                                                                         \
        *(float4*)&sA[BUF][0][ar][aseg * 8] = rh;                             \
        *(float4*)&sA[BUF][1][ar][aseg * 8] = rl;                             \
        *(float4*)&sB[BUF][bhl][brow][bseg * 8] = rb;                         \
    }
#define COMPUTEK(BUF)                                                         \
    {                                                                         \
        bf16x8 ah, al, bh[4], bl[4];                                          \
        ah = *(const bf16x8*)&sA[BUF][0][16 * w + lr][lk * 8];                \
        al = *(const bf16x8*)&sA[BUF][1][16 * w + lr][lk * 8];                \
        _Pragma("unroll")                                                     \
        for (int j = 0; j < 4; ++j) {                                         \
            bh[j] = *(const bf16x8*)&sB[BUF][0][16 * j + lr][lk * 8];         \
            bl[j] = *(const bf16x8*)&sB[BUF][1][16 * j + lr][lk * 8];         \
        }                                                                     \
        _Pragma("unroll")                                                     \
        for (int j = 0; j < 4; ++j) {                                         \
            acc[j] = __builtin_amdgcn_mfma_f32_16x16x32_bf16(ah, bh[j], acc[j], 0, 0, 0); \
            acc[j] = __builtin_amdgcn_mfma_f32_16x16x32_bf16(ah, bl[j], acc[j], 0, 0, 0); \
            acc[j] = __builtin_amdgcn_mfma_f32_16x16x32_bf16(al, bh[j], acc[j], 0, 0, 0); \
        }                                                                     \
    }

    LOADK(0)
    WRITEK(0)
    asm volatile("s_waitcnt lgkmcnt(0)" ::: "memory");
    __builtin_amdgcn_s_barrier();

    int cur = 0;
    for (int ks = 0; ks < 30; ++ks) {
        int knext = (ks < 29 ? ks + 1 : 29) * 32;
        LOADK(knext)
        COMPUTEK(cur)
        WRITEK(cur ^ 1)
        asm volatile("s_waitcnt lgkmcnt(0)" ::: "memory");
        __builtin_amdgcn_s_barrier();
        cur ^= 1;
    }

#pragma unroll
    for (int j = 0; j < 4; ++j)
#pragma unroll
        for (int jr = 0; jr < 4; ++jr) {
            int row = bm + 16 * w + lk * 4 + jr;
            int col = bn + 16 * j + lr;
            C[(size_t)row * ldc + col] = acc[j][jr];
        }
#undef COMPUTEK
#undef WRITEK
#undef LOADK
}

// ---------------------------------------------------------------------------
// plain f32 GEMM (LoRA paths): C[M,N] = A[M,K] @ B[K,N]
// ---------------------------------------------------------------------------
__global__ __launch_bounds__(256) void gemm64_kernel(
    const float* __restrict__ A, int lda,
    const float* __restrict__ Bw, int ldb,
    float* __restrict__ Cc, int ldc, int N, int K)
{
    __shared__ float As[16][68];
    __shared__ float Bs[16][64];
    int bm = blockIdx.x * 64, bn = blockIdx.y * 64;
    int tid = threadIdx.x;
    int tx = tid & 15, ty = tid >> 4;
    int ar = tid >> 2, ak = (tid & 3) * 4;
    int bkr = tid >> 4, bnc = (tid & 15) * 4;
    bool bok = (bn + bnc) < N;
    const float* Aptr = A + (size_t)(bm + ar) * lda + ak;
    const float* Bptr = Bw + (size_t)bkr * ldb + bn + bnc;
    float acc[4][4];
#pragma unroll
    for (int i = 0; i < 4; ++i)
#pragma unroll
        for (int j = 0; j < 4; ++j) acc[i][j] = 0.f;

    for (int k0 = 0; k0 < K; k0 += 16) {
        float4 a4 = *(const float4*)(Aptr + k0);
        float4 b4 = make_float4(0.f, 0.f, 0.f, 0.f);
        if (bok) b4 = *(const float4*)(Bptr + (size_t)k0 * ldb);
        As[ak + 0][ar] = a4.x;
        As[ak + 1][ar] = a4.y;
        As[ak + 2][ar] = a4.z;
        As[ak + 3][ar] = a4.w;
        *(float4*)&Bs[bkr][bnc] = b4;
        __syncthreads();
#pragma unroll
        for (int kk = 0; kk < 16; ++kk) {
            float4 av = *(const float4*)&As[kk][ty * 4];
            float4 bv = *(const float4*)&Bs[kk][tx * 4];
            float aa[4] = {av.x, av.y, av.z, av.w};
            float bb[4] = {bv.x, bv.y, bv.z, bv.w};
#pragma unroll
            for (int i = 0; i < 4; ++i)
#pragma unroll
                for (int j = 0; j < 4; ++j) acc[i][j] += aa[i] * bb[j];
        }
        __syncthreads();
    }
    if (bok) {
#pragma unroll
        for (int i = 0; i < 4; ++i) {
            int row = bm + ty * 4 + i;
            float4 st = make_float4(acc[i][0], acc[i][1], acc[i][2], acc[i][3]);
            *(float4*)(Cc + (size_t)row * ldc + bn + tx * 4) = st;
        }
    }
}

// ---------------------------------------------------------------------------
// activations on hid: cols [0,64) tanh (w), [160,288) sigmoid (g)
// ---------------------------------------------------------------------------
__global__ __launch_bounds__(256) void hidact_kernel(float* hid)
{
    int idx = blockIdx.x * 256 + threadIdx.x;
    if (idx >= Mn * 288) return;
    int c = idx % 288;
    float v = hid[idx];
    if (c < 64) v = tanhf(v);
    else if (c >= 160) v = sigmf(v);
    hid[idx] = v;
}

// ---------------------------------------------------------------------------
// elementwise stage 3: w, a, v-residual, kk-norm, kh, ah, bh.
// ---------------------------------------------------------------------------
__global__ __launch_bounds__(256) void stage3e_kernel(
    const float* wrawp, const float* aprep, const float* vsigp,
    const float* kraw, const float* vfirst,
    const float* w0, const float* a0, const float* v0c,
    const float* kkc, const float* kac,
    float* w_out, float* v_io, float* ah_out, float* bh_out, float* kh_out)
{
    int p = blockIdx.x * 4 + (threadIdx.x >> 6);
    int l = threadIdx.x & 63;
    int m = p / Hn;
    int h = p - m * Hn;
    int c = h * 64 + l;
    size_t idx = (size_t)m * Cn + c;
    float k = kraw[idx];
    float wr = w0[c] + wrawp[idx];
    float a = sigmf(a0[c] + aprep[idx]);
    float vs = sigmf(v0c[c] + vsigp[idx]);
    float v0g = v_io[idx];
    float v = v0g + (vfirst[idx] - v0g) * vs;
    float kk = k * kkc[c];
    float ss = kk * kk;
#pragma unroll
    for (int o = 32; o; o >>= 1) ss += __shfl_xor(ss, o);
    float inv = 1.0f / fmaxf(sqrtf(ss), 1e-12f);
    kk *= inv;
    float w = sigmf(wr) * 0.60653065971263342f;  // sigmoid(wr)*exp(-0.5)
    float kh = k * (1.0f + (a - 1.0f) * kac[c]);
    w_out[idx] = w;
    v_io[idx] = v;
    ah_out[idx] = -kk;
    bh_out[idx] = kk * a;
    kh_out[idx] = kh;
}

// ---------------------------------------------------------------------------
// CHUNKED scan: TWO chains per block (512 thr, 8 waves -> 2 waves/SIMD so
// one chain's stalls are filled by the other). Chain = 4 waves; lane owns
// 4 rows x 4 cols. Chunk L=8 steps, double-buffered staging (issue-early /
// write-late), fused groupnorm/bonus/gate per chunk. Reductions via DPP.
// ---------------------------------------------------------------------------
__global__ __launch_bounds__(512, 1) void scan_kernel(
    const float* __restrict__ rP, const float* __restrict__ wP,
    const float* __restrict__ kP, const float* __restrict__ aP,
    const float* __restrict__ bP, const float* __restrict__ vP,
    const float* __restrict__ gP, const float* __restrict__ r_k,
    const float* __restrict__ ln_g, const float* __restrict__ ln_b,
    float* __restrict__ xog)
{
    __shared__ float buf[2][2][7][8][64];  // [chain][half][vec][step][ch] 57344 B
    __shared__ float outL[2][8][64];       // 4096 B
    int tid = threadIdx.x;
    int half = tid >> 8;        // which chain in this block
    int stid = tid & 255;
    int q = (tid >> 6) & 3;
    int l = tid & 63;
    int bh = blockIdx.x * 2 + half;
    int bb = bh / Hn, h = bh - bb * Hn;
    size_t base = (size_t)bb * Tn * Cn + h * 64;
    int rg = l >> 4, cg = l & 15;
    int row0 = 16 * q + 4 * rg;
    int c0 = 4 * cg;

    // staging: step = stid>>5 (8 steps), seg = stid&31 (float2 each)
    int sstep = stid >> 5, sseg = stid & 31;
    size_t soff = base + (size_t)sstep * Cn + sseg * 2;
    const float* pS0 = rP + soff;
    const float* pS1 = wP + soff;
    const float* pS2 = kP + soff;
    const float* pS3 = aP + soff;
    const float* pS4 = bP + soff;
    const float* pS5 = vP + soff;
    const float* pS6 = gP + soff;
    int wofs = sstep * 64 + sseg * 2;

    float2 rk2 = *(const float2*)(r_k + h * 64 + sseg * 2);
    float2 lg2 = *(const float2*)(ln_g + h * 64 + sseg * 2);
    float2 lb2 = *(const float2*)(ln_b + h * 64 + sseg * 2);

    float s[4][4];
#pragma unroll
    for (int r = 0; r < 4; ++r)
#pragma unroll
        for (int c = 0; c < 4; ++c) s[r][c] = 0.f;

    // ---- stage chunk 0
    {
        float2 g0 = *(const float2*)pS0;
        float2 g1 = *(const float2*)pS1;
        float2 g2 = *(const float2*)pS2;
        float2 g3 = *(const float2*)pS3;
        float2 g4 = *(const float2*)pS4;
        float2 g5 = *(const float2*)pS5;
        float2 g6 = *(const float2*)pS6;
        float* bn = &buf[half][0][0][0][0];
        *(float2*)(bn + 0 * 512 + wofs) = g0;
        *(float2*)(bn + 1 * 512 + wofs) = g1;
        *(float2*)(bn + 2 * 512 + wofs) = g2;
        *(float2*)(bn + 3 * 512 + wofs) = g3;
        *(float2*)(bn + 4 * 512 + wofs) = g4;
        *(float2*)(bn + 5 * 512 + wofs) = g5;
        *(float2*)(bn + 6 * 512 + wofs) = g6;
        asm volatile("s_waitcnt lgkmcnt(0)" ::: "memory");
        __builtin_amdgcn_s_barrier();
    }

    int cur = 0;
    for (int c = 0; c < 128; ++c) {
        const float* bc = &buf[half][cur][0][0][0];
        // issue staging loads for chunk c+1
        size_t t2 = (size_t)((c < 127 ? c + 1 : 127) * 8) * Cn;
        float2 g0 = *(const float2*)(pS0 + t2);
        float2 g1 = *(const float2*)(pS1 + t2);
        float2 g2 = *(const float2*)(pS2 + t2);
        float2 g3 = *(const float2*)(pS3 + t2);
        float2 g4 = *(const float2*)(pS4 + t2);
        float2 g5 = *(const float2*)(pS5 + t2);
        float2 g6 = *(const float2*)(pS6 + t2);

#pragma unroll
        for (int t = 0; t < 8; ++t) {
            float4 av = *(const float4*)(bc + 3 * 512 + t * 64 + c0);
            float sp0 = s[0][0] * av.x + s[0][1] * av.y + s[0][2] * av.z + s[0][3] * av.w;
            float sp1 = s[1][0] * av.x + s[1][1] * av.y + s[1][2] * av.z + s[1][3] * av.w;
            float sp2 = s[2][0] * av.x + s[2][1] * av.y + s[2][2] * av.z + s[2][3] * av.w;
            float sp3 = s[3][0] * av.x + s[3][1] * av.y + s[3][2] * av.z + s[3][3] * av.w;
            sp0 = rowsum16(sp0);
            sp1 = rowsum16(sp1);
            sp2 = rowsum16(sp2);
            sp3 = rowsum16(sp3);
            float4 wv = *(const float4*)(bc + 1 * 512 + t * 64 + c0);
            float4 kv = *(const float4*)(bc + 2 * 512 + t * 64 + c0);
            float4 bv = *(const float4*)(bc + 4 * 512 + t * 64 + c0);
            float4 rv = *(const float4*)(bc + 0 * 512 + t * 64 + c0);
            float4 vv = *(const float4*)(bc + 5 * 512 + t * 64 + row0);
            float sa[4] = {sp0, sp1, sp2, sp3};
            float vr[4] = {vv.x, vv.y, vv.z, vv.w};
            float op[4];
#pragma unroll
            for (int r = 0; r < 4; ++r) {
                s[r][0] = s[r][0] * wv.x + sa[r] * bv.x + vr[r] * kv.x;
                float o = s[r][0] * rv.x;
                s[r][1] = s[r][1] * wv.y + sa[r] * bv.y + vr[r] * kv.y;
                o += s[r][1] * rv.y;
                s[r][2] = s[r][2] * wv.z + sa[r] * bv.z + vr[r] * kv.z;
                o += s[r][2] * rv.z;
                s[r][3] = s[r][3] * wv.w + sa[r] * bv.w + vr[r] * kv.w;
                o += s[r][3] * rv.w;
                op[r] = rowsum16(o);
            }
            if (cg == 0)
                *(float4*)&outL[half][t][row0] = make_float4(op[0], op[1], op[2], op[3]);
        }

        // park staged regs into the other LDS half
        {
            float* bn = &buf[half][cur ^ 1][0][0][0];
            *(float2*)(bn + 0 * 512 + wofs) = g0;
            *(float2*)(bn + 1 * 512 + wofs) = g1;
            *(float2*)(bn + 2 * 512 + wofs) = g2;
            *(float2*)(bn + 3 * 512 + wofs) = g3;
            *(float2*)(bn + 4 * 512 + wofs) = g4;
            *(float2*)(bn + 5 * 512 + wofs) = g5;
            *(float2*)(bn + 6 * 512 + wofs) = g6;
        }
        asm volatile("s_waitcnt lgkmcnt(0)" ::: "memory");
        __builtin_amdgcn_s_barrier();

        // ---- fused groupnorm + bonus + gate (thread: step=sstep, 2 cols)
        {
            float2 o2 = *(const float2*)&outL[half][sstep][sseg * 2];
            float2 r2 = *(const float2*)(bc + 0 * 512 + sstep * 64 + sseg * 2);
            float2 k2 = *(const float2*)(bc + 2 * 512 + sstep * 64 + sseg * 2);
            float2 v2 = *(const float2*)(bc + 5 * 512 + sstep * 64 + sseg * 2);
            float2 gg2 = *(const float2*)(bc + 6 * 512 + sstep * 64 + sseg * 2);
            float m1 = o2.x + o2.y;
            float m2 = o2.x * o2.x + o2.y * o2.y;
            float bd = r2.x * k2.x * rk2.x + r2.y * k2.y * rk2.y;
#pragma unroll
            for (int o = 16; o; o >>= 1) {
                m1 += __shfl_xor(m1, o);
                m2 += __shfl_xor(m2, o);
                bd += __shfl_xor(bd, o);
            }
            float mean = m1 * (1.f / 64.f);
            float var = m2 * (1.f / 64.f) - mean * mean;
            float is = rsqrtf(var + 0.00064f);
            float2 xo;
            xo.x = ((o2.x - mean) * is * lg2.x + lb2.x + bd * v2.x) * gg2.x;
            xo.y = ((o2.y - mean) * is * lg2.y + lb2.y + bd * v2.y) * gg2.y;
            *(float2*)(xog + base + ((size_t)c * 8 + sstep) * Cn + sseg * 2) = xo;
        }
        __builtin_amdgcn_s_barrier();
        cur ^= 1;
    }
}

// ---------------------------------------------------------------------------
extern "C" void kernel_launch(void* const* d_in, const int* in_sizes, int n_in,
                              void* d_out, int out_size, void* d_ws, size_t ws_size,
                              hipStream_t stream)
{
    const float* x       = (const float*)d_in[0];
    const float* v_first = (const float*)d_in[1];
    const float* x_r     = (const float*)d_in[2];
    const float* x_w     = (const float*)d_in[3];
    const float* x_k     = (const float*)d_in[4];
    const float* x_v     = (const float*)d_in[5];
    const float* x_a     = (const float*)d_in[6];
    const float* x_g     = (const float*)d_in[7];
    const float* w0      = (const float*)d_in[8];
    const float* w1      = (const float*)d_in[9];
    const float* w2      = (const float*)d_in[10];
    const float* a0      = (const float*)d_in[11];
    const float* a1      = (const float*)d_in[12];
    const float* a2      = (const float*)d_in[13];
    const float* v0c     = (const float*)d_in[14];
    const float* v1      = (const float*)d_in[15];
    const float* v2      = (const float*)d_in[16];
    const float* g1w     = (const float*)d_in[17];
    const float* g2w     = (const float*)d_in[18];
    const float* k_k     = (const float*)d_in[19];
    const float* k_a     = (const float*)d_in[20];
    const float* r_k     = (const float*)d_in[21];
    const float* Wr      = (const float*)d_in[22];
    const float* Wk      = (const float*)d_in[23];
    const float* Wv      = (const float*)d_in[24];
    const float* Wo      = (const float*)d_in[25];
    const float* ln_g    = (const float*)d_in[26];
    const float* ln_b    = (const float*)d_in[27];
    float* out = (float*)d_out;

    float* ws = (float*)d_ws;
    float* B0 = ws + 0 * MCc;  // xr split pair -> wraw -> ah
    float* B1 = ws + 1 * MCc;  // xw -> w -> xog
    float* B2 = ws + 2 * MCc;  // xk split pair -> apre -> bh
    float* B3 = ws + 3 * MCc;  // xv f32 -> vsigp -> kh
    float* B4 = ws + 4 * MCc;  // xa -> xog-split scratch (bf16)
    float* B5 = ws + 5 * MCc;  // xg -> g
    float* B6 = ws + 6 * MCc;  // r
    float* B7 = ws + 7 * MCc;  // k (raw)
    float* B8 = ws + 8 * MCc;  // v0 -> v
    float* hid = ws + 9 * MCc; // [Mn,288] f32; also scratch for W-splits

    ushort* XRsp = (ushort*)B0;   // xr split pair
    ushort* XKsp = (ushort*)B2;   // xk split pair
    ushort* XVsp = (ushort*)out;  // xv split pair (d_out scratch until stage 5)
    ushort* Whi = (ushort*)hid;   // W-split lives in hid when hid is dead
    ushort* Wlo = Whi + (size_t)960 * 960;
    ushort* Xhi = (ushort*)B4;    // xog-split (B4 dead after lora-down)
    ushort* Xlo = Xhi + MCc;

    // mix + fused split-convert for the r/k/v GEMM inputs
    mix6_kernel<<<3840, 256, 0, stream>>>(x, x_r, x_w, x_k, x_v, x_a, x_g,
                                          XRsp, B1, XKsp, B3, XVsp, B4, B5);

    dim3 gW(30, 30);
    dim3 gM(32, 15);
    // stage 1: big projections via split-bf16 MFMA
    convWT_kernel<<<gW, 256, 0, stream>>>(Wr, Whi, Wlo);
    gemm_bf3_kernel<<<gM, 512, 0, stream>>>(XRsp, XRsp + MCc, Whi, Wlo, B6, Cn);
    convWT_kernel<<<gW, 256, 0, stream>>>(Wk, Whi, Wlo);
    gemm_bf3_kernel<<<gM, 512, 0, stream>>>(XKsp, XKsp + MCc, Whi, Wlo, B7, Cn);
    convWT_kernel<<<gW, 256, 0, stream>>>(Wv, Whi, Wlo);
    gemm_bf3_kernel<<<gM, 512, 0, stream>>>(XVsp, XVsp + MCc, Whi, Wlo, B8, Cn);

    // stage 2: lora-down GEMMs into hid (f32; overwrites W-split scratch)
    dim3 g64(64, 1);
    gemm64_kernel<<<g64, 256, 0, stream>>>(B1, Cn, w1, 64, hid + 0, 288, 64, Cn);
    gemm64_kernel<<<g64, 256, 0, stream>>>(B4, Cn, a1, 64, hid + 64, 288, 64, Cn);
    gemm64_kernel<<<g64, 256, 0, stream>>>(B3, Cn, v1, 32, hid + 128, 288, 32, Cn);
    gemm64_kernel<<<dim3(64, 2), 256, 0, stream>>>(B5, Cn, g1w, 128, hid + 160, 288, 128, Cn);
    hidact_kernel<<<4608, 256, 0, stream>>>(hid);
    // stage 3: lora-up GEMMs
    gemm64_kernel<<<dim3(64, 15), 256, 0, stream>>>(hid + 0, 288, w2, Cn, B0, Cn, Cn, 64);
    gemm64_kernel<<<dim3(64, 15), 256, 0, stream>>>(hid + 64, 288, a2, Cn, B2, Cn, Cn, 64);
    gemm64_kernel<<<dim3(64, 15), 256, 0, stream>>>(hid + 128, 288, v2, Cn, B3, Cn, Cn, 32);
    gemm64_kernel<<<dim3(64, 15), 256, 0, stream>>>(hid + 160, 288, g2w, Cn, B5, Cn, Cn, 128);
    // stage 3e: elementwise + head-norm
    stage3e_kernel<<<15360, 256, 0, stream>>>(B0, B2, B3, B7, v_first,
                                              w0, a0, v0c, k_k, k_a,
                                              B1, B8, B0, B2, B3);
    // stage 4: chunked 2-chain scan + fused groupnorm/bonus/gate -> xog in B1
    scan_kernel<<<30, 512, 0, stream>>>(B6, B1, B3, B0, B2, B8, B5,
                                        r_k, ln_g, ln_b, B1);
    // stage 5: output projection via split-bf16 MFMA
    convWT_kernel<<<gW, 256, 0, stream>>>(Wo, Whi, Wlo);
    convA_kernel<<<3840, 256, 0, stream>>>(B1, Xhi, Xlo);
    gemm_bf3_kernel<<<gM, 512, 0, stream>>>(Xhi, Xlo, Whi, Wlo, out, Cn);
}

// Round 10
// 650.889 us; speedup vs baseline: 1.5829x; 1.5829x over previous
//
#include <hip/hip_runtime.h>
#include <hip/hip_bf16.h>
#include <math.h>

#define Tn 1024
#define Cn 960
#define Hn 15
#define Nn 64
#define Mn 4096  // B*T

typedef short bf16x8 __attribute__((ext_vector_type(8)));
typedef float f32x4 __attribute__((ext_vector_type(4)));

#define MCc ((size_t)Mn * Cn)

__device__ __forceinline__ float sigmf(float x) { return 1.0f / (1.0f + __expf(-x)); }

// round-to-nearest-even f32 -> bf16 (as ushort)
__device__ __forceinline__ ushort f2bf(float x) {
    unsigned u = __float_as_uint(x);
    unsigned r = (u + 0x7FFFu + ((u >> 16) & 1u)) >> 16;
    return (ushort)r;
}
__device__ __forceinline__ float bf2f(ushort h) { return __uint_as_float(((unsigned)h) << 16); }

// full sum over the 16-lane DPP row via row_ror rotate-accumulate (all VALU).
__device__ __forceinline__ float rowsum16(float x) {
    x += __int_as_float(__builtin_amdgcn_update_dpp(0, __float_as_int(x), 0x121, 0xF, 0xF, true)); // ror:1
    x += __int_as_float(__builtin_amdgcn_update_dpp(0, __float_as_int(x), 0x122, 0xF, 0xF, true)); // ror:2
    x += __int_as_float(__builtin_amdgcn_update_dpp(0, __float_as_int(x), 0x124, 0xF, 0xF, true)); // ror:4
    x += __int_as_float(__builtin_amdgcn_update_dpp(0, __float_as_int(x), 0x128, 0xF, 0xF, true)); // ror:8
    return x;
}

// ---------------------------------------------------------------------------
// token-shift + 6 mixes; r/k/v emitted as split-bf16 pairs (hi @p, lo @p+MC),
// w/v/a/g emitted f32.
// ---------------------------------------------------------------------------
__global__ __launch_bounds__(256) void mix6_kernel(
    const float* __restrict__ x,
    const float* __restrict__ mr, const float* __restrict__ mw, const float* __restrict__ mk,
    const float* __restrict__ mv, const float* __restrict__ ma, const float* __restrict__ mg,
    ushort* __restrict__ r_sp, float* __restrict__ o_w, ushort* __restrict__ k_sp,
    float* __restrict__ o_v, ushort* __restrict__ v_sp,
    float* __restrict__ o_a, float* __restrict__ o_g)
{
    int idx = blockIdx.x * 256 + threadIdx.x;  // float4 index
    int e = idx * 4;
    if (e >= Mn * Cn) return;
    int m = e / Cn;
    int c = e - m * Cn;
    int t = m & (Tn - 1);
    float4 xv = *(const float4*)(x + e);
    float4 xp = make_float4(0.f, 0.f, 0.f, 0.f);
    if (t > 0) xp = *(const float4*)(x + e - Cn);
    float4 dx = make_float4(xp.x - xv.x, xp.y - xv.y, xp.z - xv.z, xp.w - xv.w);
#define MIXV(MIXP, O)                                                         \
    float4 O;                                                                 \
    {                                                                         \
        float4 mm = *(const float4*)(MIXP + c);                               \
        O = make_float4(xv.x + dx.x * mm.x, xv.y + dx.y * mm.y,               \
                        xv.z + dx.z * mm.z, xv.w + dx.w * mm.w);              \
    }
#define SPLITW(O, P)                                                          \
    {                                                                         \
        ushort h0 = f2bf(O.x), h1 = f2bf(O.y), h2 = f2bf(O.z), h3 = f2bf(O.w);\
        ushort l0 = f2bf(O.x - bf2f(h0)), l1 = f2bf(O.y - bf2f(h1));          \
        ushort l2 = f2bf(O.z - bf2f(h2)), l3 = f2bf(O.w - bf2f(h3));          \
        *(ushort4*)(P + e) = make_ushort4(h0, h1, h2, h3);                    \
        *(ushort4*)(P + MCc + e) = make_ushort4(l0, l1, l2, l3);              \
    }
    MIXV(mr, orv) SPLITW(orv, r_sp)
    MIXV(mw, owv) *(float4*)(o_w + e) = owv;
    MIXV(mk, okv) SPLITW(okv, k_sp)
    MIXV(mv, ovv) *(float4*)(o_v + e) = ovv; SPLITW(ovv, v_sp)
    MIXV(ma, oav) *(float4*)(o_a + e) = oav;
    MIXV(mg, ogv) *(float4*)(o_g + e) = ogv;
#undef SPLITW
#undef MIXV
}

// ---------------------------------------------------------------------------
// transpose + split-convert weight: W f32 [K=960][N=960] -> Thi/Tlo bf16 [N][K]
// ---------------------------------------------------------------------------
__global__ __launch_bounds__(256) void convWT_kernel(
    const float* __restrict__ W, ushort* __restrict__ Thi, ushort* __restrict__ Tlo)
{
    __shared__ float tile[32][33];
    int k0 = blockIdx.x * 32, n0 = blockIdx.y * 32;
    int tx = threadIdx.x & 31, ty = threadIdx.x >> 5;  // 32 x 8
#pragma unroll
    for (int i = 0; i < 4; ++i)
        tile[ty + 8 * i][tx] = W[(size_t)(k0 + ty + 8 * i) * 960 + n0 + tx];
    __syncthreads();
#pragma unroll
    for (int i = 0; i < 4; ++i) {
        float x = tile[tx][ty + 8 * i];
        ushort h = f2bf(x);
        ushort l = f2bf(x - bf2f(h));
        size_t o = (size_t)(n0 + ty + 8 * i) * 960 + k0 + tx;
        Thi[o] = h;
        Tlo[o] = l;
    }
}

// ---------------------------------------------------------------------------
// split-bf16 MFMA GEMM, 512 threads / 8 waves: C = A @ W, K=960, via
// Ahi@Whi + Ahi@Wlo + Alo@Whi.  BM=128 BN=64 BK=32.
// ---------------------------------------------------------------------------
__global__ __launch_bounds__(512) void gemm_bf3_kernel(
    const ushort* __restrict__ Ahi, const ushort* __restrict__ Alo,
    const ushort* __restrict__ Bhi, const ushort* __restrict__ Blo,
    float* __restrict__ C, int ldc)
{
    __shared__ __align__(16) ushort sA[2][2][128][40];  // 40960 B
    __shared__ __align__(16) ushort sB[2][2][64][40];   // 20480 B
    const int K = 960;
    int bm = blockIdx.x * 128, bn = blockIdx.y * 64;
    int t = threadIdx.x;
    int w = t >> 6, l = t & 63;
    int lr = l & 15, lk = l >> 4;

    int ar = t >> 2, aseg = t & 3;
    int brr = t >> 2;
    int bhl = brr >> 6, brow = brr & 63, bseg = t & 3;
    const ushort* gAh = Ahi + (size_t)(bm + ar) * K + aseg * 8;
    const ushort* gAl = Alo + (size_t)(bm + ar) * K + aseg * 8;
    const ushort* gB = (bhl ? Blo : Bhi) + (size_t)(bn + brow) * K + bseg * 8;

    f32x4 acc[4];
#pragma unroll
    for (int j = 0; j < 4; ++j)
#pragma unroll
        for (int e = 0; e < 4; ++e) acc[j][e] = 0.f;

    float4 rh, rl, rb;
#define LOADK(KOFF)                                                           \
    {                                                                         \
        rh = *(const float4*)(gAh + (KOFF));                                  \
        rl = *(const float4*)(gAl + (KOFF));                                  \
        rb = *(const float4*)(gB + (KOFF));                                   \
    }
#define WRITEK(BUF)                                                           \
    {                                                                         \
        *(float4*)&sA[BUF][0][ar][aseg * 8] = rh;                             \
        *(float4*)&sA[BUF][1][ar][aseg * 8] = rl;                             \
        *(float4*)&sB[BUF][bhl][brow][bseg * 8] = rb;                         \
    }
#define COMPUTEK(BUF)                                                         \
    {                                                                         \
        bf16x8 ah, al, bh[4], bl[4];                                          \
        ah = *(const bf16x8*)&sA[BUF][0][16 * w + lr][lk * 8];                \
        al = *(const bf16x8*)&sA[BUF][1][16 * w + lr][lk * 8];                \
        _Pragma("unroll")                                                     \
        for (int j = 0; j < 4; ++j) {                                         \
            bh[j] = *(const bf16x8*)&sB[BUF][0][16 * j + lr][lk * 8];         \
            bl[j] = *(const bf16x8*)&sB[BUF][1][16 * j + lr][lk * 8];         \
        }                                                                     \
        _Pragma("unroll")                                                     \
        for (int j = 0; j < 4; ++j) {                                         \
            acc[j] = __builtin_amdgcn_mfma_f32_16x16x32_bf16(ah, bh[j], acc[j], 0, 0, 0); \
            acc[j] = __builtin_amdgcn_mfma_f32_16x16x32_bf16(ah, bl[j], acc[j], 0, 0, 0); \
            acc[j] = __builtin_amdgcn_mfma_f32_16x16x32_bf16(al, bh[j], acc[j], 0, 0, 0); \
        }                                                                     \
    }

    LOADK(0)
    WRITEK(0)
    asm volatile("s_waitcnt lgkmcnt(0)" ::: "memory");
    __builtin_amdgcn_s_barrier();

    int cur = 0;
    for (int ks = 0; ks < 30; ++ks) {
        int knext = (ks < 29 ? ks + 1 : 29) * 32;
        LOADK(knext)
        COMPUTEK(cur)
        WRITEK(cur ^ 1)
        asm volatile("s_waitcnt lgkmcnt(0)" ::: "memory");
        __builtin_amdgcn_s_barrier();
        cur ^= 1;
    }

#pragma unroll
    for (int j = 0; j < 4; ++j)
#pragma unroll
        for (int jr = 0; jr < 4; ++jr) {
            int row = bm + 16 * w + lk * 4 + jr;
            int col = bn + 16 * j + lr;
            C[(size_t)row * ldc + col] = acc[j][jr];
        }
#undef COMPUTEK
#undef WRITEK
#undef LOADK
}

// ---------------------------------------------------------------------------
// f32 tile GEMM core used by the merged LoRA kernels.
// BM=64 BN=64 BK=16, 256 threads, 4x4 per thread.  ACT: 0=none 1=tanh 2=sigm
// ---------------------------------------------------------------------------
__device__ __forceinline__ void gemm64_core(
    const float* A, int lda, const float* Bw, int ldb,
    float* Cc, int ldc, int N, int K, int bm, int bn, int act)
{
    __shared__ float As[16][68];
    __shared__ float Bs[16][64];
    int tid = threadIdx.x;
    int tx = tid & 15, ty = tid >> 4;
    int ar = tid >> 2, ak = (tid & 3) * 4;
    int bkr = tid >> 4, bnc = (tid & 15) * 4;
    bool bok = (bn + bnc) < N;
    const float* Aptr = A + (size_t)(bm + ar) * lda + ak;
    const float* Bptr = Bw + (size_t)bkr * ldb + bn + bnc;
    float acc[4][4];
#pragma unroll
    for (int i = 0; i < 4; ++i)
#pragma unroll
        for (int j = 0; j < 4; ++j) acc[i][j] = 0.f;

    for (int k0 = 0; k0 < K; k0 += 16) {
        float4 a4 = *(const float4*)(Aptr + k0);
        float4 b4 = make_float4(0.f, 0.f, 0.f, 0.f);
        if (bok) b4 = *(const float4*)(Bptr + (size_t)k0 * ldb);
        As[ak + 0][ar] = a4.x;
        As[ak + 1][ar] = a4.y;
        As[ak + 2][ar] = a4.z;
        As[ak + 3][ar] = a4.w;
        *(float4*)&Bs[bkr][bnc] = b4;
        __syncthreads();
#pragma unroll
        for (int kk = 0; kk < 16; ++kk) {
            float4 av = *(const float4*)&As[kk][ty * 4];
            float4 bv = *(const float4*)&Bs[kk][tx * 4];
            float aa[4] = {av.x, av.y, av.z, av.w};
            float bb[4] = {bv.x, bv.y, bv.z, bv.w};
#pragma unroll
            for (int i = 0; i < 4; ++i)
#pragma unroll
                for (int j = 0; j < 4; ++j) acc[i][j] += aa[i] * bb[j];
        }
        __syncthreads();
    }
    if (bok) {
#pragma unroll
        for (int i = 0; i < 4; ++i) {
            float4 st = make_float4(acc[i][0], acc[i][1], acc[i][2], acc[i][3]);
            if (act == 1) {
                st.x = tanhf(st.x); st.y = tanhf(st.y);
                st.z = tanhf(st.z); st.w = tanhf(st.w);
            } else if (act == 2) {
                st.x = sigmf(st.x); st.y = sigmf(st.y);
                st.z = sigmf(st.z); st.w = sigmf(st.w);
            }
            int row = bm + ty * 4 + i;
            *(float4*)(Cc + (size_t)row * ldc + bn + tx * 4) = st;
        }
    }
}

// merged LoRA-down: one dispatch, grid (64,5): y=0 w1(tanh), 1 a1, 2 v1,
// 3/4 g1(sigmoid).  C = hid[Mn][288] column blocks.
__global__ __launch_bounds__(256) void lora_down_kernel(
    const float* __restrict__ xw, const float* __restrict__ xa,
    const float* __restrict__ xv, const float* __restrict__ xg,
    const float* __restrict__ w1, const float* __restrict__ a1,
    const float* __restrict__ v1, const float* __restrict__ g1,
    float* __restrict__ hid)
{
    int bm = blockIdx.x * 64;
    int y = blockIdx.y;
    if (y == 0)      gemm64_core(xw, Cn, w1, 64,  hid + 0,   288, 64,  Cn, bm, 0, 1);
    else if (y == 1) gemm64_core(xa, Cn, a1, 64,  hid + 64,  288, 64,  Cn, bm, 0, 0);
    else if (y == 2) gemm64_core(xv, Cn, v1, 32,  hid + 128, 288, 32,  Cn, bm, 0, 0);
    else             gemm64_core(xg, Cn, g1, 128, hid + 160, 288, 128, Cn, bm, (y - 3) * 64, 2);
}

// merged LoRA-up: one dispatch, grid (64,15,4): z=0 w2->B0, 1 a2->B2,
// 2 v2->B3, 3 g2->B5.
__global__ __launch_bounds__(256) void lora_up_kernel(
    const float* __restrict__ hid,
    const float* __restrict__ w2, const float* __restrict__ a2,
    const float* __restrict__ v2, const float* __restrict__ g2,
    float* __restrict__ oW, float* __restrict__ oA,
    float* __restrict__ oV, float* __restrict__ oG)
{
    int bm = blockIdx.x * 64, bn = blockIdx.y * 64;
    int z = blockIdx.z;
    if (z == 0)      gemm64_core(hid + 0,   288, w2, Cn, oW, Cn, Cn, 64,  bm, bn, 0);
    else if (z == 1) gemm64_core(hid + 64,  288, a2, Cn, oA, Cn, Cn, 64,  bm, bn, 0);
    else if (z == 2) gemm64_core(hid + 128, 288, v2, Cn, oV, Cn, Cn, 32,  bm, bn, 0);
    else             gemm64_core(hid + 160, 288, g2, Cn, oG, Cn, Cn, 128, bm, bn, 0);
}

// ---------------------------------------------------------------------------
// elementwise stage 3: w, a, v-residual, kk-norm, kh, ah, bh.
// ---------------------------------------------------------------------------
__global__ __launch_bounds__(256) void stage3e_kernel(
    const float* wrawp, const float* aprep, const float* vsigp,
    const float* kraw, const float* vfirst,
    const float* w0, const float* a0, const float* v0c,
    const float* kkc, const float* kac,
    float* w_out, float* v_io, float* ah_out, float* bh_out, float* kh_out)
{
    int p = blockIdx.x * 4 + (threadIdx.x >> 6);
    int l = threadIdx.x & 63;
    int m = p / Hn;
    int h = p - m * Hn;
    int c = h * 64 + l;
    size_t idx = (size_t)m * Cn + c;
    float k = kraw[idx];
    float wr = w0[c] + wrawp[idx];
    float a = sigmf(a0[c] + aprep[idx]);
    float vs = sigmf(v0c[c] + vsigp[idx]);
    float v0g = v_io[idx];
    float v = v0g + (vfirst[idx] - v0g) * vs;
    float kk = k * kkc[c];
    float ss = kk * kk;
#pragma unroll
    for (int o = 32; o; o >>= 1) ss += __shfl_xor(ss, o);
    float inv = 1.0f / fmaxf(sqrtf(ss), 1e-12f);
    kk *= inv;
    float w = sigmf(wr) * 0.60653065971263342f;  // sigmoid(wr)*exp(-0.5)
    float kh = k * (1.0f + (a - 1.0f) * kac[c]);
    w_out[idx] = w;
    v_io[idx] = v;
    ah_out[idx] = -kk;
    bh_out[idx] = kk * a;
    kh_out[idx] = kh;
}

// ---------------------------------------------------------------------------
// CHUNKED scan (R8 structure, 308us known-good): one block (4 waves) per
// chain, 4x4 lane tile, 16-step chunks double-buffered, fused
// groupnorm/bonus/gate; output written as split-bf16 pair (fused convA).
// ---------------------------------------------------------------------------
__global__ __launch_bounds__(256, 1) void scan_kernel(
    const float* __restrict__ rP, const float* __restrict__ wP,
    const float* __restrict__ kP, const float* __restrict__ aP,
    const float* __restrict__ bP, const float* __restrict__ vP,
    const float* __restrict__ gP, const float* __restrict__ r_k,
    const float* __restrict__ ln_g, const float* __restrict__ ln_b,
    ushort* __restrict__ xsp)
{
    __shared__ float buf[2][7][16][64];  // 56 KB
    __shared__ float outL[16][64];       // 4 KB
    int tid = threadIdx.x;
    int q = tid >> 6, l = tid & 63;
    int bh = blockIdx.x;
    int bb = bh / Hn, h = bh - bb * Hn;
    size_t base = (size_t)bb * Tn * Cn + h * 64;
    int rg = l >> 4, cg = l & 15;
    int row0 = 16 * q + 4 * rg;
    int c0 = 4 * cg;

    size_t soff = base + (size_t)(tid >> 4) * Cn + (tid & 15) * 4;
    const float* pS0 = rP + soff;
    const float* pS1 = wP + soff;
    const float* pS2 = kP + soff;
    const float* pS3 = aP + soff;
    const float* pS4 = bP + soff;
    const float* pS5 = vP + soff;
    const float* pS6 = gP + soff;
    int wofs = (tid >> 4) * 64 + (tid & 15) * 4;

    int tt = tid >> 4, cc = tid & 15;
    float4 rk4 = *(const float4*)(r_k + h * 64 + 4 * cc);
    float4 lg4 = *(const float4*)(ln_g + h * 64 + 4 * cc);
    float4 lb4 = *(const float4*)(ln_b + h * 64 + 4 * cc);

    float s[4][4];
#pragma unroll
    for (int r = 0; r < 4; ++r)
#pragma unroll
        for (int c = 0; c < 4; ++c) s[r][c] = 0.f;

    {
        float4 g0 = *(const float4*)pS0;
        float4 g1 = *(const float4*)pS1;
        float4 g2 = *(const float4*)pS2;
        float4 g3 = *(const float4*)pS3;
        float4 g4 = *(const float4*)pS4;
        float4 g5 = *(const float4*)pS5;
        float4 g6 = *(const float4*)pS6;
        float* bn = &buf[0][0][0][0];
        *(float4*)(bn + 0 * 1024 + wofs) = g0;
        *(float4*)(bn + 1 * 1024 + wofs) = g1;
        *(float4*)(bn + 2 * 1024 + wofs) = g2;
        *(float4*)(bn + 3 * 1024 + wofs) = g3;
        *(float4*)(bn + 4 * 1024 + wofs) = g4;
        *(float4*)(bn + 5 * 1024 + wofs) = g5;
        *(float4*)(bn + 6 * 1024 + wofs) = g6;
        asm volatile("s_waitcnt lgkmcnt(0)" ::: "memory");
        __builtin_amdgcn_s_barrier();
    }

    int cur = 0;
    for (int c = 0; c < 64; ++c) {
        const float* bc = &buf[cur][0][0][0];
        size_t t2 = (size_t)((c < 63 ? c + 1 : 63) * 16) * Cn;
        float4 g0 = *(const float4*)(pS0 + t2);
        float4 g1 = *(const float4*)(pS1 + t2);
        float4 g2 = *(const float4*)(pS2 + t2);
        float4 g3 = *(const float4*)(pS3 + t2);
        float4 g4 = *(const float4*)(pS4 + t2);
        float4 g5 = *(const float4*)(pS5 + t2);
        float4 g6 = *(const float4*)(pS6 + t2);

#pragma unroll
        for (int t = 0; t < 16; ++t) {
            float4 av = *(const float4*)(bc + 3 * 1024 + t * 64 + c0);
            float sp0 = s[0][0] * av.x + s[0][1] * av.y + s[0][2] * av.z + s[0][3] * av.w;
            float sp1 = s[1][0] * av.x + s[1][1] * av.y + s[1][2] * av.z + s[1][3] * av.w;
            float sp2 = s[2][0] * av.x + s[2][1] * av.y + s[2][2] * av.z + s[2][3] * av.w;
            float sp3 = s[3][0] * av.x + s[3][1] * av.y + s[3][2] * av.z + s[3][3] * av.w;
            sp0 = rowsum16(sp0);
            sp1 = rowsum16(sp1);
            sp2 = rowsum16(sp2);
            sp3 = rowsum16(sp3);
            float4 wv = *(const float4*)(bc + 1 * 1024 + t * 64 + c0);
            float4 kv = *(const float4*)(bc + 2 * 1024 + t * 64 + c0);
            float4 bv = *(const float4*)(bc + 4 * 1024 + t * 64 + c0);
            float4 rv = *(const float4*)(bc + 0 * 1024 + t * 64 + c0);
            float4 vv = *(const float4*)(bc + 5 * 1024 + t * 64 + row0);
            float sa[4] = {sp0, sp1, sp2, sp3};
            float vr[4] = {vv.x, vv.y, vv.z, vv.w};
            float op[4];
#pragma unroll
            for (int r = 0; r < 4; ++r) {
                s[r][0] = s[r][0] * wv.x + sa[r] * bv.x + vr[r] * kv.x;
                float o = s[r][0] * rv.x;
                s[r][1] = s[r][1] * wv.y + sa[r] * bv.y + vr[r] * kv.y;
                o += s[r][1] * rv.y;
                s[r][2] = s[r][2] * wv.z + sa[r] * bv.z + vr[r] * kv.z;
                o += s[r][2] * rv.z;
                s[r][3] = s[r][3] * wv.w + sa[r] * bv.w + vr[r] * kv.w;
                o += s[r][3] * rv.w;
                op[r] = rowsum16(o);
            }
            if (cg == 0)
                *(float4*)&outL[t][row0] = make_float4(op[0], op[1], op[2], op[3]);
        }

        {
            float* bn = &buf[cur ^ 1][0][0][0];
            *(float4*)(bn + 0 * 1024 + wofs) = g0;
            *(float4*)(bn + 1 * 1024 + wofs) = g1;
            *(float4*)(bn + 2 * 1024 + wofs) = g2;
            *(float4*)(bn + 3 * 1024 + wofs) = g3;
            *(float4*)(bn + 4 * 1024 + wofs) = g4;
            *(float4*)(bn + 5 * 1024 + wofs) = g5;
            *(float4*)(bn + 6 * 1024 + wofs) = g6;
        }
        asm volatile("s_waitcnt lgkmcnt(0)" ::: "memory");
        __builtin_amdgcn_s_barrier();

        // ---- fused groupnorm + bonus + gate; write split-bf16 pair
        {
            float4 o4 = *(const float4*)&outL[tt][4 * cc];
            float4 r4 = *(const float4*)(bc + 0 * 1024 + tt * 64 + 4 * cc);
            float4 k4 = *(const float4*)(bc + 2 * 1024 + tt * 64 + 4 * cc);
            float4 v4 = *(const float4*)(bc + 5 * 1024 + tt * 64 + 4 * cc);
            float4 gg4 = *(const float4*)(bc + 6 * 1024 + tt * 64 + 4 * cc);
            float m1 = o4.x + o4.y + o4.z + o4.w;
            float m2 = o4.x * o4.x + o4.y * o4.y + o4.z * o4.z + o4.w * o4.w;
            float bd = r4.x * k4.x * rk4.x + r4.y * k4.y * rk4.y +
                       r4.z * k4.z * rk4.z + r4.w * k4.w * rk4.w;
            m1 = rowsum16(m1);
            m2 = rowsum16(m2);
            bd = rowsum16(bd);
            float mean = m1 * (1.f / 64.f);
            float var = m2 * (1.f / 64.f) - mean * mean;
            float is = rsqrtf(var + 0.00064f);
            float xo0 = ((o4.x - mean) * is * lg4.x + lb4.x + bd * v4.x) * gg4.x;
            float xo1 = ((o4.y - mean) * is * lg4.y + lb4.y + bd * v4.y) * gg4.y;
            float xo2 = ((o4.z - mean) * is * lg4.z + lb4.z + bd * v4.z) * gg4.z;
            float xo3 = ((o4.w - mean) * is * lg4.w + lb4.w + bd * v4.w) * gg4.w;
            ushort h0 = f2bf(xo0), h1 = f2bf(xo1), h2 = f2bf(xo2), h3 = f2bf(xo3);
            ushort l0 = f2bf(xo0 - bf2f(h0)), l1 = f2bf(xo1 - bf2f(h1));
            ushort l2 = f2bf(xo2 - bf2f(h2)), l3 = f2bf(xo3 - bf2f(h3));
            size_t gt = (size_t)c * 16 + tt;
            size_t eo = base + gt * Cn + 4 * cc;
            *(ushort4*)(xsp + eo) = make_ushort4(h0, h1, h2, h3);
            *(ushort4*)(xsp + MCc + eo) = make_ushort4(l0, l1, l2, l3);
        }
        __builtin_amdgcn_s_barrier();
        cur ^= 1;
    }
}

// ---------------------------------------------------------------------------
extern "C" void kernel_launch(void* const* d_in, const int* in_sizes, int n_in,
                              void* d_out, int out_size, void* d_ws, size_t ws_size,
                              hipStream_t stream)
{
    const float* x       = (const float*)d_in[0];
    const float* v_first = (const float*)d_in[1];
    const float* x_r     = (const float*)d_in[2];
    const float* x_w     = (const float*)d_in[3];
    const float* x_k     = (const float*)d_in[4];
    const float* x_v     = (const float*)d_in[5];
    const float* x_a     = (const float*)d_in[6];
    const float* x_g     = (const float*)d_in[7];
    const float* w0      = (const float*)d_in[8];
    const float* w1      = (const float*)d_in[9];
    const float* w2      = (const float*)d_in[10];
    const float* a0      = (const float*)d_in[11];
    const float* a1      = (const float*)d_in[12];
    const float* a2      = (const float*)d_in[13];
    const float* v0c     = (const float*)d_in[14];
    const float* v1      = (const float*)d_in[15];
    const float* v2      = (const float*)d_in[16];
    const float* g1w     = (const float*)d_in[17];
    const float* g2w     = (const float*)d_in[18];
    const float* k_k     = (const float*)d_in[19];
    const float* k_a     = (const float*)d_in[20];
    const float* r_k     = (const float*)d_in[21];
    const float* Wr      = (const float*)d_in[22];
    const float* Wk      = (const float*)d_in[23];
    const float* Wv      = (const float*)d_in[24];
    const float* Wo      = (const float*)d_in[25];
    const float* ln_g    = (const float*)d_in[26];
    const float* ln_b    = (const float*)d_in[27];
    float* out = (float*)d_out;

    float* ws = (float*)d_ws;
    float* B0 = ws + 0 * MCc;  // xr split pair -> wraw -> ah
    float* B1 = ws + 1 * MCc;  // xw -> w
    float* B2 = ws + 2 * MCc;  // xk split pair -> apre -> bh
    float* B3 = ws + 3 * MCc;  // xv f32 -> vsigp -> kh
    float* B4 = ws + 4 * MCc;  // xa -> xog split pair (scan out)
    float* B5 = ws + 5 * MCc;  // xg -> g
    float* B6 = ws + 6 * MCc;  // r
    float* B7 = ws + 7 * MCc;  // k (raw)
    float* B8 = ws + 8 * MCc;  // v0 -> v
    float* hid = ws + 9 * MCc; // [Mn,288] f32; also scratch for W-splits

    ushort* XRsp = (ushort*)B0;   // xr split pair
    ushort* XKsp = (ushort*)B2;   // xk split pair
    ushort* XVsp = (ushort*)out;  // xv split pair (d_out scratch until stage 5)
    ushort* Whi = (ushort*)hid;   // W-split in hid when hid is dead
    ushort* Wlo = Whi + (size_t)960 * 960;
    ushort* Xsp = (ushort*)B4;    // scan output split pair

    mix6_kernel<<<3840, 256, 0, stream>>>(x, x_r, x_w, x_k, x_v, x_a, x_g,
                                          XRsp, B1, XKsp, B3, XVsp, B4, B5);

    dim3 gW(30, 30);
    dim3 gM(32, 15);
    // stage 1: big projections via split-bf16 MFMA
    convWT_kernel<<<gW, 256, 0, stream>>>(Wr, Whi, Wlo);
    gemm_bf3_kernel<<<gM, 512, 0, stream>>>(XRsp, XRsp + MCc, Whi, Wlo, B6, Cn);
    convWT_kernel<<<gW, 256, 0, stream>>>(Wk, Whi, Wlo);
    gemm_bf3_kernel<<<gM, 512, 0, stream>>>(XKsp, XKsp + MCc, Whi, Wlo, B7, Cn);
    convWT_kernel<<<gW, 256, 0, stream>>>(Wv, Whi, Wlo);
    gemm_bf3_kernel<<<gM, 512, 0, stream>>>(XVsp, XVsp + MCc, Whi, Wlo, B8, Cn);

    // stage 2: merged LoRA-down (fused activations)
    lora_down_kernel<<<dim3(64, 5), 256, 0, stream>>>(B1, B4, B3, B5,
                                                      w1, a1, v1, g1w, hid);
    // stage 3: merged LoRA-up
    lora_up_kernel<<<dim3(64, 15, 4), 256, 0, stream>>>(hid, w2, a2, v2, g2w,
                                                        B0, B2, B3, B5);
    // Wo split now (hid dead after lora_up) so it's off the critical path
    convWT_kernel<<<gW, 256, 0, stream>>>(Wo, Whi, Wlo);
    // stage 3e: elementwise + head-norm
    stage3e_kernel<<<15360, 256, 0, stream>>>(B0, B2, B3, B7, v_first,
                                              w0, a0, v0c, k_k, k_a,
                                              B1, B8, B0, B2, B3);
    // stage 4: chunked scan + fused norm/bonus/gate -> split pair in B4
    scan_kernel<<<60, 256, 0, stream>>>(B6, B1, B3, B0, B2, B8, B5,
                                        r_k, ln_g, ln_b, Xsp);
    // stage 5: output projection
    gemm_bf3_kernel<<<gM, 512, 0, stream>>>(Xsp, Xsp + MCc, Whi, Wlo, out, Cn);
}

// Round 11
// 600.292 us; speedup vs baseline: 1.7164x; 1.0843x over previous
//
#include <hip/hip_runtime.h>
#include <hip/hip_bf16.h>
#include <math.h>

#define Tn 1024
#define Cn 960
#define Hn 15
#define Nn 64
#define Mn 4096  // B*T

typedef short bf16x8 __attribute__((ext_vector_type(8)));
typedef float f32x4 __attribute__((ext_vector_type(4)));

#define MCc ((size_t)Mn * Cn)

__device__ __forceinline__ float sigmf(float x) { return 1.0f / (1.0f + __expf(-x)); }

// round-to-nearest-even f32 -> bf16 (as ushort)
__device__ __forceinline__ ushort f2bf(float x) {
    unsigned u = __float_as_uint(x);
    unsigned r = (u + 0x7FFFu + ((u >> 16) & 1u)) >> 16;
    return (ushort)r;
}
__device__ __forceinline__ float bf2f(ushort h) { return __uint_as_float(((unsigned)h) << 16); }

// full sum over the 16-lane DPP row via row_ror rotate-accumulate (all VALU).
__device__ __forceinline__ float rowsum16(float x) {
    x += __int_as_float(__builtin_amdgcn_update_dpp(0, __float_as_int(x), 0x121, 0xF, 0xF, true)); // ror:1
    x += __int_as_float(__builtin_amdgcn_update_dpp(0, __float_as_int(x), 0x122, 0xF, 0xF, true)); // ror:2
    x += __int_as_float(__builtin_amdgcn_update_dpp(0, __float_as_int(x), 0x124, 0xF, 0xF, true)); // ror:4
    x += __int_as_float(__builtin_amdgcn_update_dpp(0, __float_as_int(x), 0x128, 0xF, 0xF, true)); // ror:8
    return x;
}

// ---------------------------------------------------------------------------
// token-shift + 6 mixes; r/k/v emitted as split-bf16 pairs (hi @p, lo @p+MC),
// w/v/a/g emitted f32.
// ---------------------------------------------------------------------------
__global__ __launch_bounds__(256) void mix6_kernel(
    const float* __restrict__ x,
    const float* __restrict__ mr, const float* __restrict__ mw, const float* __restrict__ mk,
    const float* __restrict__ mv, const float* __restrict__ ma, const float* __restrict__ mg,
    ushort* __restrict__ r_sp, float* __restrict__ o_w, ushort* __restrict__ k_sp,
    float* __restrict__ o_v, ushort* __restrict__ v_sp,
    float* __restrict__ o_a, float* __restrict__ o_g)
{
    int idx = blockIdx.x * 256 + threadIdx.x;  // float4 index
    int e = idx * 4;
    if (e >= Mn * Cn) return;
    int m = e / Cn;
    int c = e - m * Cn;
    int t = m & (Tn - 1);
    float4 xv = *(const float4*)(x + e);
    float4 xp = make_float4(0.f, 0.f, 0.f, 0.f);
    if (t > 0) xp = *(const float4*)(x + e - Cn);
    float4 dx = make_float4(xp.x - xv.x, xp.y - xv.y, xp.z - xv.z, xp.w - xv.w);
#define MIXV(MIXP, O)                                                         \
    float4 O;                                                                 \
    {                                                                         \
        float4 mm = *(const float4*)(MIXP + c);                               \
        O = make_float4(xv.x + dx.x * mm.x, xv.y + dx.y * mm.y,               \
                        xv.z + dx.z * mm.z, xv.w + dx.w * mm.w);              \
    }
#define SPLITW(O, P)                                                          \
    {                                                                         \
        ushort h0 = f2bf(O.x), h1 = f2bf(O.y), h2 = f2bf(O.z), h3 = f2bf(O.w);\
        ushort l0 = f2bf(O.x - bf2f(h0)), l1 = f2bf(O.y - bf2f(h1));          \
        ushort l2 = f2bf(O.z - bf2f(h2)), l3 = f2bf(O.w - bf2f(h3));          \
        *(ushort4*)(P + e) = make_ushort4(h0, h1, h2, h3);                    \
        *(ushort4*)(P + MCc + e) = make_ushort4(l0, l1, l2, l3);              \
    }
    MIXV(mr, orv) SPLITW(orv, r_sp)
    MIXV(mw, owv) *(float4*)(o_w + e) = owv;
    MIXV(mk, okv) SPLITW(okv, k_sp)
    MIXV(mv, ovv) *(float4*)(o_v + e) = ovv; SPLITW(ovv, v_sp)
    MIXV(ma, oav) *(float4*)(o_a + e) = oav;
    MIXV(mg, ogv) *(float4*)(o_g + e) = ogv;
#undef SPLITW
#undef MIXV
}

// ---------------------------------------------------------------------------
// transpose + split-convert weight: W f32 [K=960][N=960] -> Thi/Tlo bf16 [N][K]
// ---------------------------------------------------------------------------
__global__ __launch_bounds__(256) void convWT_kernel(
    const float* __restrict__ W, ushort* __restrict__ Thi, ushort* __restrict__ Tlo)
{
    __shared__ float tile[32][33];
    int k0 = blockIdx.x * 32, n0 = blockIdx.y * 32;
    int tx = threadIdx.x & 31, ty = threadIdx.x >> 5;  // 32 x 8
#pragma unroll
    for (int i = 0; i < 4; ++i)
        tile[ty + 8 * i][tx] = W[(size_t)(k0 + ty + 8 * i) * 960 + n0 + tx];
    __syncthreads();
#pragma unroll
    for (int i = 0; i < 4; ++i) {
        float x = tile[tx][ty + 8 * i];
        ushort h = f2bf(x);
        ushort l = f2bf(x - bf2f(h));
        size_t o = (size_t)(n0 + ty + 8 * i) * 960 + k0 + tx;
        Thi[o] = h;
        Tlo[o] = l;
    }
}

// ---------------------------------------------------------------------------
// split-bf16 MFMA GEMM, 512 threads / 8 waves: C = A @ W, K=960, via
// Ahi@Whi + Ahi@Wlo + Alo@Whi.  BM=128 BN=64 BK=32.
// ---------------------------------------------------------------------------
__global__ __launch_bounds__(512) void gemm_bf3_kernel(
    const ushort* __restrict__ Ahi, const ushort* __restrict__ Alo,
    const ushort* __restrict__ Bhi, const ushort* __restrict__ Blo,
    float* __restrict__ C, int ldc)
{
    __shared__ __align__(16) ushort sA[2][2][128][40];  // 40960 B
    __shared__ __align__(16) ushort sB[2][2][64][40];   // 20480 B
    const int K = 960;
    int bm = blockIdx.x * 128, bn = blockIdx.y * 64;
    int t = threadIdx.x;
    int w = t >> 6, l = t & 63;
    int lr = l & 15, lk = l >> 4;

    int ar = t >> 2, aseg = t & 3;
    int brr = t >> 2;
    int bhl = brr >> 6, brow = brr & 63, bseg = t & 3;
    const ushort* gAh = Ahi + (size_t)(bm + ar) * K + aseg * 8;
    const ushort* gAl = Alo + (size_t)(bm + ar) * K + aseg * 8;
    const ushort* gB = (bhl ? Blo : Bhi) + (size_t)(bn + brow) * K + bseg * 8;

    f32x4 acc[4];
#pragma unroll
    for (int j = 0; j < 4; ++j)
#pragma unroll
        for (int e = 0; e < 4; ++e) acc[j][e] = 0.f;

    float4 rh, rl, rb;
#define LOADK(KOFF)                                                           \
    {                                                                         \
        rh = *(const float4*)(gAh + (KOFF));                                  \
        rl = *(const float4*)(gAl + (KOFF));                                  \
        rb = *(const float4*)(gB + (KOFF));                                   \
    }
#define WRITEK(BUF)                                                           \
    {                                                                         \
        *(float4*)&sA[BUF][0][ar][aseg * 8] = rh;                             \
        *(float4*)&sA[BUF][1][ar][aseg * 8] = rl;                             \
        *(float4*)&sB[BUF][bhl][brow][bseg * 8] = rb;                         \
    }
#define COMPUTEK(BUF)                                                         \
    {                                                                         \
        bf16x8 ah, al, bh[4], bl[4];                                          \
        ah = *(const bf16x8*)&sA[BUF][0][16 * w + lr][lk * 8];                \
        al = *(const bf16x8*)&sA[BUF][1][16 * w + lr][lk * 8];                \
        _Pragma("unroll")                                                     \
        for (int j = 0; j < 4; ++j) {                                         \
            bh[j] = *(const bf16x8*)&sB[BUF][0][16 * j + lr][lk * 8];         \
            bl[j] = *(const bf16x8*)&sB[BUF][1][16 * j + lr][lk * 8];         \
        }                                                                     \
        _Pragma("unroll")                                                     \
        for (int j = 0; j < 4; ++j) {                                         \
            acc[j] = __builtin_amdgcn_mfma_f32_16x16x32_bf16(ah, bh[j], acc[j], 0, 0, 0); \
            acc[j] = __builtin_amdgcn_mfma_f32_16x16x32_bf16(ah, bl[j], acc[j], 0, 0, 0); \
            acc[j] = __builtin_amdgcn_mfma_f32_16x16x32_bf16(al, bh[j], acc[j], 0, 0, 0); \
        }                                                                     \
    }

    LOADK(0)
    WRITEK(0)
    asm volatile("s_waitcnt lgkmcnt(0)" ::: "memory");
    __builtin_amdgcn_s_barrier();

    int cur = 0;
    for (int ks = 0; ks < 30; ++ks) {
        int knext = (ks < 29 ? ks + 1 : 29) * 32;
        LOADK(knext)
        COMPUTEK(cur)
        WRITEK(cur ^ 1)
        asm volatile("s_waitcnt lgkmcnt(0)" ::: "memory");
        __builtin_amdgcn_s_barrier();
        cur ^= 1;
    }

#pragma unroll
    for (int j = 0; j < 4; ++j)
#pragma unroll
        for (int jr = 0; jr < 4; ++jr) {
            int row = bm + 16 * w + lk * 4 + jr;
            int col = bn + 16 * j + lr;
            C[(size_t)row * ldc + col] = acc[j][jr];
        }
#undef COMPUTEK
#undef WRITEK
#undef LOADK
}

// ---------------------------------------------------------------------------
// f32 tile GEMM core used by the merged LoRA kernels.
// BM=64 BN=64 BK=16, 256 threads, 4x4 per thread.  ACT: 0=none 1=tanh 2=sigm
// ---------------------------------------------------------------------------
__device__ __forceinline__ void gemm64_core(
    const float* A, int lda, const float* Bw, int ldb,
    float* Cc, int ldc, int N, int K, int bm, int bn, int act)
{
    __shared__ float As[16][68];
    __shared__ float Bs[16][64];
    int tid = threadIdx.x;
    int tx = tid & 15, ty = tid >> 4;
    int ar = tid >> 2, ak = (tid & 3) * 4;
    int bkr = tid >> 4, bnc = (tid & 15) * 4;
    bool bok = (bn + bnc) < N;
    const float* Aptr = A + (size_t)(bm + ar) * lda + ak;
    const float* Bptr = Bw + (size_t)bkr * ldb + bn + bnc;
    float acc[4][4];
#pragma unroll
    for (int i = 0; i < 4; ++i)
#pragma unroll
        for (int j = 0; j < 4; ++j) acc[i][j] = 0.f;

    for (int k0 = 0; k0 < K; k0 += 16) {
        float4 a4 = *(const float4*)(Aptr + k0);
        float4 b4 = make_float4(0.f, 0.f, 0.f, 0.f);
        if (bok) b4 = *(const float4*)(Bptr + (size_t)k0 * ldb);
        As[ak + 0][ar] = a4.x;
        As[ak + 1][ar] = a4.y;
        As[ak + 2][ar] = a4.z;
        As[ak + 3][ar] = a4.w;
        *(float4*)&Bs[bkr][bnc] = b4;
        __syncthreads();
#pragma unroll
        for (int kk = 0; kk < 16; ++kk) {
            float4 av = *(const float4*)&As[kk][ty * 4];
            float4 bv = *(const float4*)&Bs[kk][tx * 4];
            float aa[4] = {av.x, av.y, av.z, av.w};
            float bb[4] = {bv.x, bv.y, bv.z, bv.w};
#pragma unroll
            for (int i = 0; i < 4; ++i)
#pragma unroll
                for (int j = 0; j < 4; ++j) acc[i][j] += aa[i] * bb[j];
        }
        __syncthreads();
    }
    if (bok) {
#pragma unroll
        for (int i = 0; i < 4; ++i) {
            float4 st = make_float4(acc[i][0], acc[i][1], acc[i][2], acc[i][3]);
            if (act == 1) {
                st.x = tanhf(st.x); st.y = tanhf(st.y);
                st.z = tanhf(st.z); st.w = tanhf(st.w);
            } else if (act == 2) {
                st.x = sigmf(st.x); st.y = sigmf(st.y);
                st.z = sigmf(st.z); st.w = sigmf(st.w);
            }
            int row = bm + ty * 4 + i;
            *(float4*)(Cc + (size_t)row * ldc + bn + tx * 4) = st;
        }
    }
}

// merged LoRA-down: one dispatch, grid (64,5): y=0 w1(tanh), 1 a1, 2 v1,
// 3/4 g1(sigmoid).  C = hid[Mn][288] column blocks.
__global__ __launch_bounds__(256) void lora_down_kernel(
    const float* __restrict__ xw, const float* __restrict__ xa,
    const float* __restrict__ xv, const float* __restrict__ xg,
    const float* __restrict__ w1, const float* __restrict__ a1,
    const float* __restrict__ v1, const float* __restrict__ g1,
    float* __restrict__ hid)
{
    int bm = blockIdx.x * 64;
    int y = blockIdx.y;
    if (y == 0)      gemm64_core(xw, Cn, w1, 64,  hid + 0,   288, 64,  Cn, bm, 0, 1);
    else if (y == 1) gemm64_core(xa, Cn, a1, 64,  hid + 64,  288, 64,  Cn, bm, 0, 0);
    else if (y == 2) gemm64_core(xv, Cn, v1, 32,  hid + 128, 288, 32,  Cn, bm, 0, 0);
    else             gemm64_core(xg, Cn, g1, 128, hid + 160, 288, 128, Cn, bm, (y - 3) * 64, 2);
}

// merged LoRA-up: one dispatch, grid (64,15,4): z=0 w2->B0, 1 a2->B2,
// 2 v2->B3, 3 g2->B5.
__global__ __launch_bounds__(256) void lora_up_kernel(
    const float* __restrict__ hid,
    const float* __restrict__ w2, const float* __restrict__ a2,
    const float* __restrict__ v2, const float* __restrict__ g2,
    float* __restrict__ oW, float* __restrict__ oA,
    float* __restrict__ oV, float* __restrict__ oG)
{
    int bm = blockIdx.x * 64, bn = blockIdx.y * 64;
    int z = blockIdx.z;
    if (z == 0)      gemm64_core(hid + 0,   288, w2, Cn, oW, Cn, Cn, 64,  bm, bn, 0);
    else if (z == 1) gemm64_core(hid + 64,  288, a2, Cn, oA, Cn, Cn, 64,  bm, bn, 0);
    else if (z == 2) gemm64_core(hid + 128, 288, v2, Cn, oV, Cn, Cn, 32,  bm, bn, 0);
    else             gemm64_core(hid + 160, 288, g2, Cn, oG, Cn, Cn, 128, bm, bn, 0);
}

// ---------------------------------------------------------------------------
// elementwise stage 3: w, a, v-residual, kk-norm, kh, ah, bh.
// ---------------------------------------------------------------------------
__global__ __launch_bounds__(256) void stage3e_kernel(
    const float* wrawp, const float* aprep, const float* vsigp,
    const float* kraw, const float* vfirst,
    const float* w0, const float* a0, const float* v0c,
    const float* kkc, const float* kac,
    float* w_out, float* v_io, float* ah_out, float* bh_out, float* kh_out)
{
    int p = blockIdx.x * 4 + (threadIdx.x >> 6);
    int l = threadIdx.x & 63;
    int m = p / Hn;
    int h = p - m * Hn;
    int c = h * 64 + l;
    size_t idx = (size_t)m * Cn + c;
    float k = kraw[idx];
    float wr = w0[c] + wrawp[idx];
    float a = sigmf(a0[c] + aprep[idx]);
    float vs = sigmf(v0c[c] + vsigp[idx]);
    float v0g = v_io[idx];
    float v = v0g + (vfirst[idx] - v0g) * vs;
    float kk = k * kkc[c];
    float ss = kk * kk;
#pragma unroll
    for (int o = 32; o; o >>= 1) ss += __shfl_xor(ss, o);
    float inv = 1.0f / fmaxf(sqrtf(ss), 1e-12f);
    kk *= inv;
    float w = sigmf(wr) * 0.60653065971263342f;  // sigmoid(wr)*exp(-0.5)
    float kh = k * (1.0f + (a - 1.0f) * kac[c]);
    w_out[idx] = w;
    v_io[idx] = v;
    ah_out[idx] = -kk;
    bh_out[idx] = kk * a;
    kh_out[idx] = kh;
}

// ---------------------------------------------------------------------------
// CHUNKED scan with 2-step register double-buffer (A/B sets).
// One block (4 waves) per chain; lane owns 4 rows x 4 cols. 16-step chunks,
// double-buffered global staging (issue-early/write-late), fused
// groupnorm/bonus/gate; output written as split-bf16 pair.
// The A/B sets keep per-step ds_read latency OFF the critical path:
// set loaded >= 2 steps (~500 issue-cycles) before use.
// ---------------------------------------------------------------------------
__global__ __launch_bounds__(256, 1) void scan_kernel(
    const float* __restrict__ rP, const float* __restrict__ wP,
    const float* __restrict__ kP, const float* __restrict__ aP,
    const float* __restrict__ bP, const float* __restrict__ vP,
    const float* __restrict__ gP, const float* __restrict__ r_k,
    const float* __restrict__ ln_g, const float* __restrict__ ln_b,
    ushort* __restrict__ xsp)
{
    __shared__ float buf[2][7][16][64];  // 56 KB
    __shared__ float outL[16][64];       // 4 KB
    int tid = threadIdx.x;
    int q = tid >> 6, l = tid & 63;
    int bh = blockIdx.x;
    int bb = bh / Hn, h = bh - bb * Hn;
    size_t base = (size_t)bb * Tn * Cn + h * 64;
    int rg = l >> 4, cg = l & 15;
    int row0 = 16 * q + 4 * rg;
    int c0 = 4 * cg;

    size_t soff = base + (size_t)(tid >> 4) * Cn + (tid & 15) * 4;
    const float* pS0 = rP + soff;
    const float* pS1 = wP + soff;
    const float* pS2 = kP + soff;
    const float* pS3 = aP + soff;
    const float* pS4 = bP + soff;
    const float* pS5 = vP + soff;
    const float* pS6 = gP + soff;
    int wofs = (tid >> 4) * 64 + (tid & 15) * 4;

    int tt = tid >> 4, cc = tid & 15;
    float4 rk4 = *(const float4*)(r_k + h * 64 + 4 * cc);
    float4 lg4 = *(const float4*)(ln_g + h * 64 + 4 * cc);
    float4 lb4 = *(const float4*)(ln_b + h * 64 + 4 * cc);

    float s[4][4];
#pragma unroll
    for (int r = 0; r < 4; ++r)
#pragma unroll
        for (int c = 0; c < 4; ++c) s[r][c] = 0.f;

    {
        float4 g0 = *(const float4*)pS0;
        float4 g1 = *(const float4*)pS1;
        float4 g2 = *(const float4*)pS2;
        float4 g3 = *(const float4*)pS3;
        float4 g4 = *(const float4*)pS4;
        float4 g5 = *(const float4*)pS5;
        float4 g6 = *(const float4*)pS6;
        float* bn = &buf[0][0][0][0];
        *(float4*)(bn + 0 * 1024 + wofs) = g0;
        *(float4*)(bn + 1 * 1024 + wofs) = g1;
        *(float4*)(bn + 2 * 1024 + wofs) = g2;
        *(float4*)(bn + 3 * 1024 + wofs) = g3;
        *(float4*)(bn + 4 * 1024 + wofs) = g4;
        *(float4*)(bn + 5 * 1024 + wofs) = g5;
        *(float4*)(bn + 6 * 1024 + wofs) = g6;
        asm volatile("s_waitcnt lgkmcnt(0)" ::: "memory");
        __builtin_amdgcn_s_barrier();
    }

// ---- 2-step register sets ------------------------------------------------
#define DECL2(S)                                                              \
    float4 S##a0, S##w0, S##k0, S##b0, S##r0, S##v0;                          \
    float4 S##a1, S##w1, S##k1, S##b1, S##r1, S##v1;
#define DSLOAD2(S, T)                                                         \
    S##a0 = *(const float4*)(bc + 3 * 1024 + (T) * 64 + c0);                  \
    S##w0 = *(const float4*)(bc + 1 * 1024 + (T) * 64 + c0);                  \
    S##k0 = *(const float4*)(bc + 2 * 1024 + (T) * 64 + c0);                  \
    S##b0 = *(const float4*)(bc + 4 * 1024 + (T) * 64 + c0);                  \
    S##r0 = *(const float4*)(bc + 0 * 1024 + (T) * 64 + c0);                  \
    S##v0 = *(const float4*)(bc + 5 * 1024 + (T) * 64 + row0);                \
    S##a1 = *(const float4*)(bc + 3 * 1024 + ((T) + 1) * 64 + c0);            \
    S##w1 = *(const float4*)(bc + 1 * 1024 + ((T) + 1) * 64 + c0);            \
    S##k1 = *(const float4*)(bc + 2 * 1024 + ((T) + 1) * 64 + c0);            \
    S##b1 = *(const float4*)(bc + 4 * 1024 + ((T) + 1) * 64 + c0);            \
    S##r1 = *(const float4*)(bc + 0 * 1024 + ((T) + 1) * 64 + c0);            \
    S##v1 = *(const float4*)(bc + 5 * 1024 + ((T) + 1) * 64 + row0);
#define STEP(AV, WV, KV, BV, RV, VV, T)                                       \
    {                                                                         \
        float sp0 = s[0][0] * AV.x + s[0][1] * AV.y + s[0][2] * AV.z + s[0][3] * AV.w; \
        float sp1 = s[1][0] * AV.x + s[1][1] * AV.y + s[1][2] * AV.z + s[1][3] * AV.w; \
        float sp2 = s[2][0] * AV.x + s[2][1] * AV.y + s[2][2] * AV.z + s[2][3] * AV.w; \
        float sp3 = s[3][0] * AV.x + s[3][1] * AV.y + s[3][2] * AV.z + s[3][3] * AV.w; \
        sp0 = rowsum16(sp0);                                                  \
        sp1 = rowsum16(sp1);                                                  \
        sp2 = rowsum16(sp2);                                                  \
        sp3 = rowsum16(sp3);                                                  \
        float sa[4] = {sp0, sp1, sp2, sp3};                                   \
        float vr[4] = {VV.x, VV.y, VV.z, VV.w};                               \
        float op[4];                                                          \
        _Pragma("unroll")                                                     \
        for (int r = 0; r < 4; ++r) {                                         \
            s[r][0] = s[r][0] * WV.x + sa[r] * BV.x + vr[r] * KV.x;           \
            float o = s[r][0] * RV.x;                                         \
            s[r][1] = s[r][1] * WV.y + sa[r] * BV.y + vr[r] * KV.y;           \
            o += s[r][1] * RV.y;                                              \
            s[r][2] = s[r][2] * WV.z + sa[r] * BV.z + vr[r] * KV.z;           \
            o += s[r][2] * RV.z;                                              \
            s[r][3] = s[r][3] * WV.w + sa[r] * BV.w + vr[r] * KV.w;           \
            o += s[r][3] * RV.w;                                              \
            op[r] = rowsum16(o);                                              \
        }                                                                     \
        if (cg == 0)                                                          \
            *(float4*)&outL[T][row0] = make_float4(op[0], op[1], op[2], op[3]); \
    }

    DECL2(A) DECL2(B)

    int cur = 0;
    for (int c = 0; c < 64; ++c) {
        const float* bc = &buf[cur][0][0][0];
        // issue staging loads for chunk c+1 (latency hidden under 16 steps)
        size_t t2 = (size_t)((c < 63 ? c + 1 : 63) * 16) * Cn;
        float4 g0 = *(const float4*)(pS0 + t2);
        float4 g1 = *(const float4*)(pS1 + t2);
        float4 g2 = *(const float4*)(pS2 + t2);
        float4 g3 = *(const float4*)(pS3 + t2);
        float4 g4 = *(const float4*)(pS4 + t2);
        float4 g5 = *(const float4*)(pS5 + t2);
        float4 g6 = *(const float4*)(pS6 + t2);

        // 16 steps, A/B 2-step register double-buffer
        DSLOAD2(A, 0)
#pragma unroll
        for (int it = 0; it < 4; ++it) {
            DSLOAD2(B, 4 * it + 2)
            STEP(Aa0, Aw0, Ak0, Ab0, Ar0, Av0, 4 * it + 0)
            STEP(Aa1, Aw1, Ak1, Ab1, Ar1, Av1, 4 * it + 1)
            if (it < 3) { DSLOAD2(A, 4 * it + 4) }
            STEP(Ba0, Bw0, Bk0, Bb0, Br0, Bv0, 4 * it + 2)
            STEP(Ba1, Bw1, Bk1, Bb1, Br1, Bv1, 4 * it + 3)
        }

        // park staged regs into the other LDS half
        {
            float* bn = &buf[cur ^ 1][0][0][0];
            *(float4*)(bn + 0 * 1024 + wofs) = g0;
            *(float4*)(bn + 1 * 1024 + wofs) = g1;
            *(float4*)(bn + 2 * 1024 + wofs) = g2;
            *(float4*)(bn + 3 * 1024 + wofs) = g3;
            *(float4*)(bn + 4 * 1024 + wofs) = g4;
            *(float4*)(bn + 5 * 1024 + wofs) = g5;
            *(float4*)(bn + 6 * 1024 + wofs) = g6;
        }
        asm volatile("s_waitcnt lgkmcnt(0)" ::: "memory");
        __builtin_amdgcn_s_barrier();

        // ---- fused groupnorm + bonus + gate; write split-bf16 pair
        {
            float4 o4 = *(const float4*)&outL[tt][4 * cc];
            float4 r4 = *(const float4*)(bc + 0 * 1024 + tt * 64 + 4 * cc);
            float4 k4 = *(const float4*)(bc + 2 * 1024 + tt * 64 + 4 * cc);
            float4 v4 = *(const float4*)(bc + 5 * 1024 + tt * 64 + 4 * cc);
            float4 gg4 = *(const float4*)(bc + 6 * 1024 + tt * 64 + 4 * cc);
            float m1 = o4.x + o4.y + o4.z + o4.w;
            float m2 = o4.x * o4.x + o4.y * o4.y + o4.z * o4.z + o4.w * o4.w;
            float bd = r4.x * k4.x * rk4.x + r4.y * k4.y * rk4.y +
                       r4.z * k4.z * rk4.z + r4.w * k4.w * rk4.w;
            m1 = rowsum16(m1);
            m2 = rowsum16(m2);
            bd = rowsum16(bd);
            float mean = m1 * (1.f / 64.f);
            float var = m2 * (1.f / 64.f) - mean * mean;
            float is = rsqrtf(var + 0.00064f);
            float xo0 = ((o4.x - mean) * is * lg4.x + lb4.x + bd * v4.x) * gg4.x;
            float xo1 = ((o4.y - mean) * is * lg4.y + lb4.y + bd * v4.y) * gg4.y;
            float xo2 = ((o4.z - mean) * is * lg4.z + lb4.z + bd * v4.z) * gg4.z;
            float xo3 = ((o4.w - mean) * is * lg4.w + lb4.w + bd * v4.w) * gg4.w;
            ushort h0 = f2bf(xo0), h1 = f2bf(xo1), h2 = f2bf(xo2), h3 = f2bf(xo3);
            ushort l0 = f2bf(xo0 - bf2f(h0)), l1 = f2bf(xo1 - bf2f(h1));
            ushort l2 = f2bf(xo2 - bf2f(h2)), l3 = f2bf(xo3 - bf2f(h3));
            size_t gt = (size_t)c * 16 + tt;
            size_t eo = base + gt * Cn + 4 * cc;
            *(ushort4*)(xsp + eo) = make_ushort4(h0, h1, h2, h3);
            *(ushort4*)(xsp + MCc + eo) = make_ushort4(l0, l1, l2, l3);
        }
        __builtin_amdgcn_s_barrier();
        cur ^= 1;
    }
#undef STEP
#undef DSLOAD2
#undef DECL2
}

// ---------------------------------------------------------------------------
extern "C" void kernel_launch(void* const* d_in, const int* in_sizes, int n_in,
                              void* d_out, int out_size, void* d_ws, size_t ws_size,
                              hipStream_t stream)
{
    const float* x       = (const float*)d_in[0];
    const float* v_first = (const float*)d_in[1];
    const float* x_r     = (const float*)d_in[2];
    const float* x_w     = (const float*)d_in[3];
    const float* x_k     = (const float*)d_in[4];
    const float* x_v     = (const float*)d_in[5];
    const float* x_a     = (const float*)d_in[6];
    const float* x_g     = (const float*)d_in[7];
    const float* w0      = (const float*)d_in[8];
    const float* w1      = (const float*)d_in[9];
    const float* w2      = (const float*)d_in[10];
    const float* a0      = (const float*)d_in[11];
    const float* a1      = (const float*)d_in[12];
    const float* a2      = (const float*)d_in[13];
    const float* v0c     = (const float*)d_in[14];
    const float* v1      = (const float*)d_in[15];
    const float* v2      = (const float*)d_in[16];
    const float* g1w     = (const float*)d_in[17];
    const float* g2w     = (const float*)d_in[18];
    const float* k_k     = (const float*)d_in[19];
    const float* k_a     = (const float*)d_in[20];
    const float* r_k     = (const float*)d_in[21];
    const float* Wr      = (const float*)d_in[22];
    const float* Wk      = (const float*)d_in[23];
    const float* Wv      = (const float*)d_in[24];
    const float* Wo      = (const float*)d_in[25];
    const float* ln_g    = (const float*)d_in[26];
    const float* ln_b    = (const float*)d_in[27];
    float* out = (float*)d_out;

    float* ws = (float*)d_ws;
    float* B0 = ws + 0 * MCc;  // xr split pair -> wraw -> ah
    float* B1 = ws + 1 * MCc;  // xw -> w
    float* B2 = ws + 2 * MCc;  // xk split pair -> apre -> bh
    float* B3 = ws + 3 * MCc;  // xv f32 -> vsigp -> kh
    float* B4 = ws + 4 * MCc;  // xa -> xog split pair (scan out)
    float* B5 = ws + 5 * MCc;  // xg -> g
    float* B6 = ws + 6 * MCc;  // r
    float* B7 = ws + 7 * MCc;  // k (raw)
    float* B8 = ws + 8 * MCc;  // v0 -> v
    float* hid = ws + 9 * MCc; // [Mn,288] f32; also scratch for W-splits

    ushort* XRsp = (ushort*)B0;   // xr split pair
    ushort* XKsp = (ushort*)B2;   // xk split pair
    ushort* XVsp = (ushort*)out;  // xv split pair (d_out scratch until stage 5)
    ushort* Whi = (ushort*)hid;   // W-split in hid when hid is dead
    ushort* Wlo = Whi + (size_t)960 * 960;
    ushort* Xsp = (ushort*)B4;    // scan output split pair

    mix6_kernel<<<3840, 256, 0, stream>>>(x, x_r, x_w, x_k, x_v, x_a, x_g,
                                          XRsp, B1, XKsp, B3, XVsp, B4, B5);

    dim3 gW(30, 30);
    dim3 gM(32, 15);
    // stage 1: big projections via split-bf16 MFMA
    convWT_kernel<<<gW, 256, 0, stream>>>(Wr, Whi, Wlo);
    gemm_bf3_kernel<<<gM, 512, 0, stream>>>(XRsp, XRsp + MCc, Whi, Wlo, B6, Cn);
    convWT_kernel<<<gW, 256, 0, stream>>>(Wk, Whi, Wlo);
    gemm_bf3_kernel<<<gM, 512, 0, stream>>>(XKsp, XKsp + MCc, Whi, Wlo, B7, Cn);
    convWT_kernel<<<gW, 256, 0, stream>>>(Wv, Whi, Wlo);
    gemm_bf3_kernel<<<gM, 512, 0, stream>>>(XVsp, XVsp + MCc, Whi, Wlo, B8, Cn);

    // stage 2: merged LoRA-down (fused activations)
    lora_down_kernel<<<dim3(64, 5), 256, 0, stream>>>(B1, B4, B3, B5,
                                                      w1, a1, v1, g1w, hid);
    // stage 3: merged LoRA-up
    lora_up_kernel<<<dim3(64, 15, 4), 256, 0, stream>>>(hid, w2, a2, v2, g2w,
                                                        B0, B2, B3, B5);
    // Wo split now (hid dead after lora_up) so it's off the critical path
    convWT_kernel<<<gW, 256, 0, stream>>>(Wo, Whi, Wlo);
    // stage 3e: elementwise + head-norm
    stage3e_kernel<<<15360, 256, 0, stream>>>(B0, B2, B3, B7, v_first,
                                              w0, a0, v0c, k_k, k_a,
                                              B1, B8, B0, B2, B3);
    // stage 4: chunked scan + fused norm/bonus/gate -> split pair in B4
    scan_kernel<<<60, 256, 0, stream>>>(B6, B1, B3, B0, B2, B8, B5,
                                        r_k, ln_g, ln_b, Xsp);
    // stage 5: output projection
    gemm_bf3_kernel<<<gM, 512, 0, stream>>>(Xsp, Xsp + MCc, Whi, Wlo, out, Cn);
}